// Round 9
// baseline (291.686 us; speedup 1.0000x reference)
//
#include <hip/hip_runtime.h>
#include <math.h>

// DNA-GNN: N=100000, E=3200000, C=8, HEADS=2, d_head=4, 3 layers.
// glin GROUPS=8, cin=cout=1 => per-channel scale+bias.
//
// Round 25: SoA-by-layer compact gather tables (L2-locality play).
//   r24 evidence: agg3 FETCH 88MB vs 20MB working set (4.4x over-fetch);
//   64B U rows spread 6.4MB across every XCD's 4MB L2 -> thrash ->
//   gathers pay L3/HBM latency. Replace A/U with:
//     H0,H1,H2: n x 16B  (layer outputs, fp16 x8)
//     NRM:      n x 4B   (dinv, gathered per-src by agg1)
//     ND:       n x 8B   (dinv, SN) per dst for layers 2/3
//   Hot sets: agg1 2.0MB, agg2 3.2MB (fits XCD L2), agg3 4.8MB (nearly).
//   Requests/edge unchanged (2/2/3 x 16B) - pure latency/hit-rate win.
//   Carry-over from r24: ebuf prefetch rotation, Li=2 sigmoid softmax,
//   no-NT ebuf in aggs, q15(dinv_src) in ebuf bits 17..31 from agg<1>,
//   exact SN in ND.y, no-max exp2 softmax, single-pass CSR, CAP 9216.

#define SBB   8
#define SBN   256
#define CH    4096
#define CAP   9216

typedef _Float16 half8 __attribute__((ext_vector_type(8)));
typedef int int4v __attribute__((ext_vector_type(4)));

__global__ void __launch_bounds__(256) phaseAC(const int* __restrict__ eidx,
                                               int* __restrict__ gcnt,
                                               int* __restrict__ ebuf,
                                               int E, int NS) {
    __shared__ int sorted_[CH];
    __shared__ unsigned short karr[CH];
    __shared__ int cntS[512];
    __shared__ int lofs[512];
    __shared__ int wbase[512];
    __shared__ int sA[512], sB[512];
    int t = threadIdx.x, b = blockIdx.x;
    int base = b * CH;
    int nEdge = E - base; if (nEdge > CH) nEdge = CH;

    for (int i = t; i < 512; i += 256) cntS[i] = 0;
    __syncthreads();

    int w[16]; short kk[16];
#pragma unroll
    for (int it = 0; it < 4; it++) {
        int e0 = base + (it * 256 + t) * 4;
        if (e0 + 3 < E) {
            int4v s4 = __builtin_nontemporal_load((const int4v*)(eidx + e0));
            int4v d4 = __builtin_nontemporal_load((const int4v*)(eidx + E + e0));
#pragma unroll
            for (int j = 0; j < 4; j++) {
                int idx = it * 4 + j;
                w[idx] = s4[j] | ((d4[j] & (SBN - 1)) << 17);
                kk[idx] = (short)(d4[j] >> SBB);
                atomicAdd(&cntS[kk[idx]], 1);
            }
        } else {
#pragma unroll
            for (int j = 0; j < 4; j++) {
                int e = e0 + j, idx = it * 4 + j;
                if (e < E) {
                    int s = eidx[e], d = eidx[E + e];
                    w[idx] = s | ((d & (SBN - 1)) << 17);
                    kk[idx] = (short)(d >> SBB);
                    atomicAdd(&cntS[kk[idx]], 1);
                } else { w[idx] = 0; kk[idx] = 511; }
            }
        }
    }
    __syncthreads();
    sA[t] = cntS[t]; sA[t + 256] = cntS[t + 256];
    __syncthreads();
    int* sp = sA; int* dp = sB;
    for (int o = 1; o < 512; o <<= 1) {
#pragma unroll
        for (int h = 0; h < 2; h++) {
            int i = t + h * 256;
            int v = sp[i];
            if (i >= o) v += sp[i - o];
            dp[i] = v;
        }
        __syncthreads();
        int* tmp = sp; sp = dp; dp = tmp;
    }
    for (int i = t; i < 512; i += 256) {
        int excl = sp[i] - cntS[i];
        lofs[i] = excl;
        if (i < NS && cntS[i] > 0) {
            int g = atomicAdd(&gcnt[i], cntS[i]);
            wbase[i] = i * CAP + g - excl;
        }
    }
    __syncthreads();
#pragma unroll
    for (int idx = 0; idx < 16; idx++) {
        if (kk[idx] != 511) {
            int p = atomicAdd(&lofs[kk[idx]], 1);
            sorted_[p] = w[idx];
            karr[p] = (unsigned short)kk[idx];
        }
    }
    __syncthreads();
    for (int i = t; i < nEdge; i += 256)
        ebuf[wbase[karr[i]] + i] = sorted_[i];
}

__global__ void super_csr(int* __restrict__ ebuf, const int* __restrict__ gcnt,
                          unsigned int* __restrict__ off, float* __restrict__ NRM,
                          float* __restrict__ ND, int NS, int n) {
    __shared__ int seg[CAP];
    __shared__ int cnt[SBN];
    __shared__ int fillp[SBN];
    __shared__ int sd[256];
    int t = threadIdx.x, k = blockIdx.x;
    cnt[t] = 0;
    int start = k * CAP;
    int len = gcnt[k];
    __syncthreads();
    for (int i = t; i < len; i += 256) {
        int w = __builtin_nontemporal_load(&ebuf[start + i]);
        seg[i] = w;
        atomicAdd(&cnt[w >> 17], 1);
    }
    __syncthreads();
    int v = cnt[t];
    sd[t] = v; __syncthreads();
    for (int o = 1; o < 256; o <<= 1) {
        int u = 0; if (t >= o) u = sd[t - o];
        __syncthreads(); sd[t] += u; __syncthreads();
    }
    int excl = sd[t] - v;
    fillp[t] = excl;
    int d = (k << SBB) + t;
    if (d < n) {
        off[d] = (unsigned int)(start + excl) | ((unsigned int)v << 22);
        float dvv = rsqrtf((float)(v + 1));   // +1 self-loop
        NRM[d] = dvv;
        ND[2 * (size_t)d] = dvv;
    }
    __syncthreads();
    for (int i = t; i < len; i += 256) {
        int w = seg[i];
        int pos = atomicAdd(&fillp[w >> 17], 1);
        ebuf[start + pos] = w & 131071;
    }
}

// h0 = relu([emb[nidx], x] @ W1 + b1) -> H0 (n x 16B); also zeroes gcnt.
__global__ void node_init(const float* __restrict__ x, const int* __restrict__ nidx,
                          const float* __restrict__ emb, const float* __restrict__ W1,
                          const float* __restrict__ b1, char* __restrict__ H0,
                          int* __restrict__ gcnt, int NS, int n) {
    int i = blockIdx.x * blockDim.x + threadIdx.x;
    if (i < NS) gcnt[i] = 0;
    if (i >= n) return;
    float in[24];
    int ni = nidx[i];
    const float4* ep = (const float4*)(emb + (size_t)ni * 8);
    float4 e0 = ep[0], e1 = ep[1];
    in[0] = e0.x; in[1] = e0.y; in[2] = e0.z; in[3] = e0.w;
    in[4] = e1.x; in[5] = e1.y; in[6] = e1.z; in[7] = e1.w;
    const float4* xp = (const float4*)(x + (size_t)i * 16);
#pragma unroll
    for (int t = 0; t < 4; t++) {
        float4 v = xp[t];
        in[8 + 4 * t + 0] = v.x; in[8 + 4 * t + 1] = v.y;
        in[8 + 4 * t + 2] = v.z; in[8 + 4 * t + 3] = v.w;
    }
    float acc[8];
#pragma unroll
    for (int j = 0; j < 8; j++) acc[j] = b1[j];
#pragma unroll
    for (int t = 0; t < 24; t++) {
        float xv = in[t];
#pragma unroll
        for (int j = 0; j < 8; j++) acc[j] = fmaf(xv, W1[t * 8 + j], acc[j]);
    }
    half8 h;
#pragma unroll
    for (int j = 0; j < 8; j++) h[j] = (_Float16)fmaxf(acc[j], 0.0f);
    *(half8*)(H0 + (size_t)i * 16) = h;
}

// 8 lanes per dst; round-robin slots (lane t owns t, t+8, ...; slot 0 =
// virtual self-loop). ebuf words prefetched one batch ahead. Gathers hit
// the compact per-layer tables H0/H1/H2 (16B rows). agg<1> packs
// q15(dinv_src) into ebuf bits 17..31 and stores exact SN at ND[d].y;
// Li>=2 decode edge norm from the ebuf word, load (nd,SN) as one float2.
template <int Li, bool LAST>
__global__ void __launch_bounds__(256)
agg_layer(int* __restrict__ ssrc, const unsigned int* __restrict__ off,
          const char* __restrict__ H0, char* __restrict__ H1,
          char* __restrict__ H2, const float* __restrict__ NRM,
          float* __restrict__ ND,
          const float* __restrict__ wq, const float* __restrict__ bq,
          const float* __restrict__ wk, const float* __restrict__ bk,
          const float* __restrict__ wv, const float* __restrict__ bv,
          const float* __restrict__ W2, const float* __restrict__ b2,
          float* __restrict__ out, int n) {
    constexpr int B = (Li == 1) ? 8 : 4;
    constexpr int STEP = 8 * B;
    int tid = blockIdx.x * blockDim.x + threadIdx.x;
    int d = tid >> 3, t = tid & 7;
    if (d >= n) return;
    unsigned int ow = off[d];
    int lo = (int)(ow & 0x3FFFFFu), cnt = (int)(ow >> 22);
    int* sp = ssrc + lo - 1;     // sp[s] = slot s's ebuf word (s >= 1)

    float nd, SN;
    if (Li == 1) {
        nd = NRM[d];
        SN = 0.f;
    } else {
        float2 nn = *(const float2*)(ND + 2 * (size_t)d);
        nd = nn.x; SN = nn.y;
    }

    float qk[8];
    if (Li >= 2) {
        half8 qh = (Li == 2) ? *(const half8*)(H1 + (size_t)d * 16)
                             : *(const half8*)(H2 + (size_t)d * 16);
#pragma unroll
        for (int c = 0; c < 8; c++) {
            float qv = fmaf((float)qh[c], wq[c], bq[c]);
            qk[c] = 0.72134752f * wk[c] * qv;  // 0.5/ln2: scores in exp2 domain
        }
    }

    float T[8];
#pragma unroll
    for (int c = 0; c < 8; c++) T[c] = 0.f;

    int total = cnt + 1;

    // prime batch 0's ebuf words
    int s0 = t;
    unsigned int wcur[B];
    int mcur = 0;
    if (s0 < total) {
        mcur = (total - s0 + 7) >> 3; if (mcur > B) mcur = B;
#pragma unroll
        for (int u = 0; u < B; u++) {
            int s = s0 + 8 * u;
            wcur[u] = 0u;
            if (u < mcur && s > 0) wcur[u] = (unsigned int)sp[s];
        }
    }

    while (s0 < total) {
        int m = mcur;
        int si[B]; float ns[B];
        half8 r[B][Li];
        // issue row gathers for the current batch
#pragma unroll
        for (int u = 0; u < B; u++) {
            if (u < m) {
                int s = s0 + 8 * u;
                si[u] = (s == 0) ? d : (int)(wcur[u] & 0x1FFFFu);
                r[u][0] = *(const half8*)(H0 + (size_t)si[u] * 16);
                if (Li >= 2) r[u][1] = *(const half8*)(H1 + (size_t)si[u] * 16);
                if (Li >= 3) r[u][2] = *(const half8*)(H2 + (size_t)si[u] * 16);
                if (Li == 1) {
                    ns[u] = (s == 0) ? nd : NRM[si[u]];
                } else {
                    ns[u] = (s == 0) ? nd : (float)(wcur[u] >> 17) * (1.0f / 32767.0f);
                }
            }
        }
        // prefetch next batch's ebuf words (overlaps with compute below)
        int s1 = s0 + STEP;
        unsigned int wnext[B];
        int mnext = 0;
        if (s1 < total) {
            mnext = (total - s1 + 7) >> 3; if (mnext > B) mnext = B;
#pragma unroll
            for (int u = 0; u < B; u++) {
                wnext[u] = 0u;
                if (u < mnext) wnext[u] = (unsigned int)sp[s1 + 8 * u];  // s1 >= 32 > 0
            }
        }
        // compute
#pragma unroll
        for (int u = 0; u < B; u++) {
            if (u < m) {
                float xs[8 * Li];
#pragma unroll
                for (int l = 0; l < Li; l++)
#pragma unroll
                    for (int c = 0; c < 8; c++) xs[l * 8 + c] = (float)r[u][l][c];
                float nv = ns[u];
                if (Li == 1) {
#pragma unroll
                    for (int c = 0; c < 8; c++) T[c] = fmaf(nv, xs[c], T[c]);
                    SN += nv;
                } else {
                    float score[2][Li];
#pragma unroll
                    for (int l = 0; l < Li; l++) {
#pragma unroll
                        for (int h = 0; h < 2; h++) {
                            float sc = 0.f;
#pragma unroll
                            for (int dd = 0; dd < 4; dd++) {
                                int c = h * 4 + dd;
                                sc = fmaf(qk[c], xs[l * 8 + c], sc);
                            }
                            score[h][l] = sc;
                        }
                    }
                    float f[2][Li];
                    if (Li == 2) {
                        // 2-way softmax = sigmoid: one exp2 per head
#pragma unroll
                        for (int h = 0; h < 2; h++) {
                            float g = exp2f(score[h][1] - score[h][0]);
                            float inv = nv * __builtin_amdgcn_rcpf(1.0f + g);
                            f[h][0] = inv; f[h][1] = inv * g;
                        }
                    } else {
                        // no max-subtraction: scores bounded, exp2 safe in f32
#pragma unroll
                        for (int h = 0; h < 2; h++) {
                            float ssum = 0.f;
#pragma unroll
                            for (int l = 0; l < Li; l++) { f[h][l] = exp2f(score[h][l]); ssum += f[h][l]; }
                            float nsh = nv * __builtin_amdgcn_rcpf(ssum);
#pragma unroll
                            for (int l = 0; l < Li; l++) f[h][l] *= nsh;
                        }
                    }
#pragma unroll
                    for (int c = 0; c < 8; c++) {
                        int h = c >> 2;
#pragma unroll
                        for (int l = 0; l < Li; l++) T[c] = fmaf(f[h][l], xs[l * 8 + c], T[c]);
                    }
                }
            }
        }
        if (Li == 1) {
            // coalesced writeback: src | q15(dinv_src) << 17
#pragma unroll
            for (int u = 0; u < B; u++) {
                int s = s0 + 8 * u;
                if (u < m && s > 0) {
                    unsigned int q = (unsigned int)(ns[u] * 32767.0f + 0.5f);
                    sp[s] = (int)(wcur[u] | (q << 17));
                }
            }
        }
        // rotate
        s0 = s1; mcur = mnext;
#pragma unroll
        for (int u = 0; u < B; u++) wcur[u] = wnext[u];
    }
#pragma unroll
    for (int m2 = 1; m2 < 8; m2 <<= 1) {
#pragma unroll
        for (int c = 0; c < 8; c++) T[c] += __shfl_xor(T[c], m2);
        if (Li == 1) SN += __shfl_xor(SN, m2);
    }
    if (!LAST) {
        float acc = fmaf(wv[t], T[t], bv[t] * SN);
        float h = fmaxf(acc * nd, 0.f);
        char* Hout = (Li == 1) ? H1 : H2;
        *(_Float16*)(Hout + (size_t)d * 16 + 2 * t) = (_Float16)h;
        if (Li == 1 && t == 1)
            ND[2 * (size_t)d + 1] = SN;   // exact SN for layers 2/3
    } else if (t == 0) {
        float z0 = b2[0], z1 = b2[1];
#pragma unroll
        for (int c = 0; c < 8; c++) {
            float acc = fmaf(wv[c], T[c], bv[c] * SN);
            float h = fmaxf(acc * nd, 0.f);
            z0 = fmaf(h, W2[c * 2 + 0], z0);
            z1 = fmaf(h, W2[c * 2 + 1], z1);
        }
        float m2 = fmaxf(z0, z1);
        float lse = m2 + logf(__expf(z0 - m2) + __expf(z1 - m2));
        ((float2*)out)[d] = make_float2(z0 - lse, z1 - lse);
    }
}

extern "C" void kernel_launch(void* const* d_in, const int* in_sizes, int n_in,
                              void* d_out, int out_size, void* d_ws, size_t ws_size,
                              hipStream_t stream) {
    const float* x    = (const float*)d_in[0];
    const int*   nidx = (const int*)d_in[1];
    const int*   eidx = (const int*)d_in[3];
    const float* emb  = (const float*)d_in[5];
    const float* W1   = (const float*)d_in[6];
    const float* b1   = (const float*)d_in[7];
    const float* Wq   = (const float*)d_in[8];
    const float* bq   = (const float*)d_in[9];
    const float* Wk   = (const float*)d_in[10];
    const float* bk   = (const float*)d_in[11];
    const float* Wv   = (const float*)d_in[12];
    const float* bv   = (const float*)d_in[13];
    const float* W2   = (const float*)d_in[14];
    const float* b2   = (const float*)d_in[15];
    float* out = (float*)d_out;

    const int n = in_sizes[0] / 16;            // 100000
    const int E = in_sizes[3] / 2;             // 3200000
    const int NS = (n + SBN - 1) / SBN;        // 391
    const int NBLK = (E + CH - 1) / CH;        // 782

    char* wsp = (char*)d_ws;
    char*  H0    = wsp;                      wsp += (size_t)n * 16;
    char*  H1    = wsp;                      wsp += (size_t)n * 16;
    char*  H2    = wsp;                      wsp += (size_t)n * 16;
    float* ND    = (float*)wsp;              wsp += (size_t)n * 8;
    float* NRM   = (float*)wsp;              wsp += (size_t)n * 4;
    int*   ebuf  = (int*)wsp;                wsp += (size_t)NS * CAP * 4;
    unsigned int* off = (unsigned int*)wsp;  wsp += (size_t)n * 4;
    int*   gcnt  = (int*)wsp;                wsp += (size_t)NS * 4;

    dim3 blk(256);
    dim3 gn((n + 255) / 256);
    dim3 ga(((size_t)n * 8 + 255) / 256);

    node_init<<<gn, blk, 0, stream>>>(x, nidx, emb, W1, b1, H0, gcnt, NS, n);
    phaseAC<<<NBLK, blk, 0, stream>>>(eidx, gcnt, ebuf, E, NS);
    super_csr<<<NS, blk, 0, stream>>>(ebuf, gcnt, off, NRM, ND, NS, n);

    agg_layer<1, false><<<ga, blk, 0, stream>>>(ebuf, off, H0, H1, H2, NRM, ND,
        Wq, bq, Wk, bk, Wv, bv, W2, b2, out, n);
    agg_layer<2, false><<<ga, blk, 0, stream>>>(ebuf, off, H0, H1, H2, NRM, ND,
        Wq + 8, bq + 8, Wk + 8, bk + 8, Wv + 8, bv + 8, W2, b2, out, n);
    agg_layer<3, true><<<ga, blk, 0, stream>>>(ebuf, off, H0, H1, H2, NRM, ND,
        Wq + 16, bq + 16, Wk + 16, bk + 16, Wv + 16, bv + 16, W2, b2, out, n);
}

// Round 10
// 269.777 us; speedup vs baseline: 1.0812x; 1.0812x over previous
//
#include <hip/hip_runtime.h>
#include <math.h>

// DNA-GNN: N=100000, E=3200000, C=8, HEADS=2, d_head=4, 3 layers.
// glin GROUPS=8, cin=cout=1 => per-channel scale+bias.
//
// Round 26: revert r25 SoA (3 tables => 3 lines/edge, FETCH 88->117MB,
// 42->63us). Back to r24 AoS: A (n x 32B: h0+dvv), U (n x 64B:
// h0,h1,h2,dvv,SN) -- one line serves all slices of a src row.
// New on top of r24:
//   1. Mixed-precision FMA: fmaf(qk, (float)h16, acc) compiles to
//      v_fma_mix_f32 -- kills 24 v_cvt per Li=3 edge and the xs[] f32
//      staging array. Bit-identical (mix converts f16 exactly).
//   2. node_init fused into phaseAC (block-range split); gcnt zeroing
//      via hipMemsetAsync (graph-capture-safe).
//   Carry-over: ebuf prefetch rotation, Li=2 sigmoid softmax, no-NT ebuf
//   in aggs, q15(dinv_src) in ebuf bits 17..31 from agg<1>, exact SN at
//   U+52, no-max exp2 softmax, single-pass CSR, CAP 9216.

#define SBB   8
#define SBN   256
#define CH    4096
#define CAP   9216

typedef _Float16 half8 __attribute__((ext_vector_type(8)));
typedef int int4v __attribute__((ext_vector_type(4)));

// Fused: blocks [0, NBLK) sort edges (phaseAC); blocks [NBLK, ...) run
// node_init: h0 = relu([emb[nidx], x] @ W1 + b1) -> A and U ch0..7.
__global__ void __launch_bounds__(256) build_init(
        const int* __restrict__ eidx, int* __restrict__ gcnt,
        int* __restrict__ ebuf, int E, int NS, int NBLK,
        const float* __restrict__ x, const int* __restrict__ nidx,
        const float* __restrict__ emb, const float* __restrict__ W1,
        const float* __restrict__ b1, char* __restrict__ A,
        char* __restrict__ U, int n) {
    __shared__ int sorted_[CH];
    __shared__ unsigned short karr[CH];
    __shared__ int cntS[512];
    __shared__ int lofs[512];
    __shared__ int wbase[512];
    __shared__ int sA[512], sB[512];
    int t = threadIdx.x, b = blockIdx.x;

    if (b >= NBLK) {
        // ---- node_init path ----
        int i = (b - NBLK) * 256 + t;
        if (i >= n) return;
        float in[24];
        int ni = nidx[i];
        const float4* ep = (const float4*)(emb + (size_t)ni * 8);
        float4 e0 = ep[0], e1 = ep[1];
        in[0] = e0.x; in[1] = e0.y; in[2] = e0.z; in[3] = e0.w;
        in[4] = e1.x; in[5] = e1.y; in[6] = e1.z; in[7] = e1.w;
        const float4* xp = (const float4*)(x + (size_t)i * 16);
#pragma unroll
        for (int tt = 0; tt < 4; tt++) {
            float4 v = xp[tt];
            in[8 + 4 * tt + 0] = v.x; in[8 + 4 * tt + 1] = v.y;
            in[8 + 4 * tt + 2] = v.z; in[8 + 4 * tt + 3] = v.w;
        }
        float acc[8];
#pragma unroll
        for (int j = 0; j < 8; j++) acc[j] = b1[j];
#pragma unroll
        for (int tt = 0; tt < 24; tt++) {
            float xv = in[tt];
#pragma unroll
            for (int j = 0; j < 8; j++) acc[j] = fmaf(xv, W1[tt * 8 + j], acc[j]);
        }
        half8 h;
#pragma unroll
        for (int j = 0; j < 8; j++) h[j] = (_Float16)fmaxf(acc[j], 0.0f);
        *(half8*)(A + (size_t)i * 32) = h;
        *(half8*)(U + (size_t)i * 64) = h;
        return;
    }

    // ---- phaseAC path ----
    int base = b * CH;
    int nEdge = E - base; if (nEdge > CH) nEdge = CH;

    for (int i = t; i < 512; i += 256) cntS[i] = 0;
    __syncthreads();

    int w[16]; short kk[16];
#pragma unroll
    for (int it = 0; it < 4; it++) {
        int e0 = base + (it * 256 + t) * 4;
        if (e0 + 3 < E) {
            int4v s4 = __builtin_nontemporal_load((const int4v*)(eidx + e0));
            int4v d4 = __builtin_nontemporal_load((const int4v*)(eidx + E + e0));
#pragma unroll
            for (int j = 0; j < 4; j++) {
                int idx = it * 4 + j;
                w[idx] = s4[j] | ((d4[j] & (SBN - 1)) << 17);
                kk[idx] = (short)(d4[j] >> SBB);
                atomicAdd(&cntS[kk[idx]], 1);
            }
        } else {
#pragma unroll
            for (int j = 0; j < 4; j++) {
                int e = e0 + j, idx = it * 4 + j;
                if (e < E) {
                    int s = eidx[e], d = eidx[E + e];
                    w[idx] = s | ((d & (SBN - 1)) << 17);
                    kk[idx] = (short)(d >> SBB);
                    atomicAdd(&cntS[kk[idx]], 1);
                } else { w[idx] = 0; kk[idx] = 511; }
            }
        }
    }
    __syncthreads();
    sA[t] = cntS[t]; sA[t + 256] = cntS[t + 256];
    __syncthreads();
    int* sp = sA; int* dp = sB;
    for (int o = 1; o < 512; o <<= 1) {
#pragma unroll
        for (int h = 0; h < 2; h++) {
            int i = t + h * 256;
            int v = sp[i];
            if (i >= o) v += sp[i - o];
            dp[i] = v;
        }
        __syncthreads();
        int* tmp = sp; sp = dp; dp = tmp;
    }
    for (int i = t; i < 512; i += 256) {
        int excl = sp[i] - cntS[i];
        lofs[i] = excl;
        if (i < NS && cntS[i] > 0) {
            int g = atomicAdd(&gcnt[i], cntS[i]);
            wbase[i] = i * CAP + g - excl;
        }
    }
    __syncthreads();
#pragma unroll
    for (int idx = 0; idx < 16; idx++) {
        if (kk[idx] != 511) {
            int p = atomicAdd(&lofs[kk[idx]], 1);
            sorted_[p] = w[idx];
            karr[p] = (unsigned short)kk[idx];
        }
    }
    __syncthreads();
    for (int i = t; i < nEdge; i += 256)
        ebuf[wbase[karr[i]] + i] = sorted_[i];
}

__global__ void super_csr(int* __restrict__ ebuf, const int* __restrict__ gcnt,
                          unsigned int* __restrict__ off, char* __restrict__ A,
                          char* __restrict__ U, int NS, int n) {
    __shared__ int seg[CAP];
    __shared__ int cnt[SBN];
    __shared__ int fillp[SBN];
    __shared__ int sd[256];
    int t = threadIdx.x, k = blockIdx.x;
    cnt[t] = 0;
    int start = k * CAP;
    int len = gcnt[k];
    __syncthreads();
    for (int i = t; i < len; i += 256) {
        int w = __builtin_nontemporal_load(&ebuf[start + i]);
        seg[i] = w;
        atomicAdd(&cnt[w >> 17], 1);
    }
    __syncthreads();
    int v = cnt[t];
    sd[t] = v; __syncthreads();
    for (int o = 1; o < 256; o <<= 1) {
        int u = 0; if (t >= o) u = sd[t - o];
        __syncthreads(); sd[t] += u; __syncthreads();
    }
    int excl = sd[t] - v;
    fillp[t] = excl;
    int d = (k << SBB) + t;
    if (d < n) {
        off[d] = (unsigned int)(start + excl) | ((unsigned int)v << 22);
        float dvv = rsqrtf((float)(v + 1));   // +1 self-loop
        *(float*)(A + (size_t)d * 32 + 16) = dvv;
        *(float*)(U + (size_t)d * 64 + 48) = dvv;
    }
    __syncthreads();
    for (int i = t; i < len; i += 256) {
        int w = seg[i];
        int pos = atomicAdd(&fillp[w >> 17], 1);
        ebuf[start + pos] = w & 131071;
    }
}

// 8 lanes per dst; round-robin slots (lane t owns t, t+8, ...; slot 0 =
// virtual self-loop). ebuf words prefetched one batch ahead. agg<1> packs
// q15(dinv_src) into ebuf bits 17..31 and stores exact SN at U+52;
// Li>=2 decode edge norm from the ebuf word, load (nd,SN) as one float2.
// All f16 operands consumed via v_fma_mix (no cvt, no f32 staging).
template <int Li, bool LAST>
__global__ void __launch_bounds__(256)
agg_layer(int* __restrict__ ssrc, const unsigned int* __restrict__ off,
          const char* __restrict__ A, char* __restrict__ U,
          const float* __restrict__ wq, const float* __restrict__ bq,
          const float* __restrict__ wk, const float* __restrict__ bk,
          const float* __restrict__ wv, const float* __restrict__ bv,
          const float* __restrict__ W2, const float* __restrict__ b2,
          float* __restrict__ out, int n) {
    constexpr int B = (Li == 1) ? 8 : 4;
    constexpr int STEP = 8 * B;
    int tid = blockIdx.x * blockDim.x + threadIdx.x;
    int d = tid >> 3, t = tid & 7;
    if (d >= n) return;
    unsigned int ow = off[d];
    int lo = (int)(ow & 0x3FFFFFu), cnt = (int)(ow >> 22);
    int* sp = ssrc + lo - 1;     // sp[s] = slot s's ebuf word (s >= 1)

    float nd, SN;
    if (Li == 1) {
        nd = *(const float*)(A + (size_t)d * 32 + 16);
        SN = 0.f;
    } else {
        float2 nn = *(const float2*)(U + (size_t)d * 64 + 48);
        nd = nn.x; SN = nn.y;
    }

    float qk[8];
    if (Li >= 2) {
        half8 qh = (Li == 2) ? *(const half8*)(U + (size_t)d * 64 + 16)
                             : *(const half8*)(U + (size_t)d * 64 + 32);
#pragma unroll
        for (int c = 0; c < 8; c++) {
            float qv = fmaf((float)qh[c], wq[c], bq[c]);
            qk[c] = 0.72134752f * wk[c] * qv;  // 0.5/ln2: scores in exp2 domain
        }
    }

    float T[8];
#pragma unroll
    for (int c = 0; c < 8; c++) T[c] = 0.f;

    int total = cnt + 1;

    // prime batch 0's ebuf words
    int s0 = t;
    unsigned int wcur[B];
    int mcur = 0;
    if (s0 < total) {
        mcur = (total - s0 + 7) >> 3; if (mcur > B) mcur = B;
#pragma unroll
        for (int u = 0; u < B; u++) {
            int s = s0 + 8 * u;
            wcur[u] = 0u;
            if (u < mcur && s > 0) wcur[u] = (unsigned int)sp[s];
        }
    }

    while (s0 < total) {
        int m = mcur;
        int si[B]; float ns[B];
        half8 r[B][Li];
        // issue row gathers for the current batch
#pragma unroll
        for (int u = 0; u < B; u++) {
            if (u < m) {
                int s = s0 + 8 * u;
                si[u] = (s == 0) ? d : (int)(wcur[u] & 0x1FFFFu);
                if (Li == 1) {
                    const char* p = A + (size_t)si[u] * 32;
                    r[u][0] = *(const half8*)p;
                    ns[u] = (s == 0) ? nd : *(const float*)(p + 16);
                } else {
                    const char* p = U + (size_t)si[u] * 64;
#pragma unroll
                    for (int l = 0; l < Li; l++) r[u][l] = *(const half8*)(p + l * 16);
                    ns[u] = (s == 0) ? nd : (float)(wcur[u] >> 17) * (1.0f / 32767.0f);
                }
            }
        }
        // prefetch next batch's ebuf words (overlaps with compute below)
        int s1 = s0 + STEP;
        unsigned int wnext[B];
        int mnext = 0;
        if (s1 < total) {
            mnext = (total - s1 + 7) >> 3; if (mnext > B) mnext = B;
#pragma unroll
            for (int u = 0; u < B; u++) {
                wnext[u] = 0u;
                if (u < mnext) wnext[u] = (unsigned int)sp[s1 + 8 * u];  // s1 >= 32 > 0
            }
        }
        // compute (all f16 reads via mixed-precision fma)
#pragma unroll
        for (int u = 0; u < B; u++) {
            if (u < m) {
                float nv = ns[u];
                if (Li == 1) {
#pragma unroll
                    for (int c = 0; c < 8; c++)
                        T[c] = fmaf(nv, (float)r[u][0][c], T[c]);
                    SN += nv;
                } else {
                    float score[2][Li];
#pragma unroll
                    for (int l = 0; l < Li; l++) {
#pragma unroll
                        for (int h = 0; h < 2; h++) {
                            float sc = 0.f;
#pragma unroll
                            for (int dd = 0; dd < 4; dd++) {
                                int c = h * 4 + dd;
                                sc = fmaf(qk[c], (float)r[u][l][c], sc);
                            }
                            score[h][l] = sc;
                        }
                    }
                    float f[2][Li];
                    if (Li == 2) {
                        // 2-way softmax = sigmoid: one exp2 per head
#pragma unroll
                        for (int h = 0; h < 2; h++) {
                            float g = exp2f(score[h][1] - score[h][0]);
                            float inv = nv * __builtin_amdgcn_rcpf(1.0f + g);
                            f[h][0] = inv; f[h][1] = inv * g;
                        }
                    } else {
                        // no max-subtraction: scores bounded, exp2 safe in f32
#pragma unroll
                        for (int h = 0; h < 2; h++) {
                            float ssum = 0.f;
#pragma unroll
                            for (int l = 0; l < Li; l++) { f[h][l] = exp2f(score[h][l]); ssum += f[h][l]; }
                            float nsh = nv * __builtin_amdgcn_rcpf(ssum);
#pragma unroll
                            for (int l = 0; l < Li; l++) f[h][l] *= nsh;
                        }
                    }
#pragma unroll
                    for (int c = 0; c < 8; c++) {
                        int h = c >> 2;
#pragma unroll
                        for (int l = 0; l < Li; l++)
                            T[c] = fmaf(f[h][l], (float)r[u][l][c], T[c]);
                    }
                }
            }
        }
        if (Li == 1) {
            // coalesced writeback: src | q15(dinv_src) << 17
#pragma unroll
            for (int u = 0; u < B; u++) {
                int s = s0 + 8 * u;
                if (u < m && s > 0) {
                    unsigned int q = (unsigned int)(ns[u] * 32767.0f + 0.5f);
                    sp[s] = (int)(wcur[u] | (q << 17));
                }
            }
        }
        // rotate
        s0 = s1; mcur = mnext;
#pragma unroll
        for (int u = 0; u < B; u++) wcur[u] = wnext[u];
    }
#pragma unroll
    for (int m2 = 1; m2 < 8; m2 <<= 1) {
#pragma unroll
        for (int c = 0; c < 8; c++) T[c] += __shfl_xor(T[c], m2);
        if (Li == 1) SN += __shfl_xor(SN, m2);
    }
    if (!LAST) {
        float acc = fmaf(wv[t], T[t], bv[t] * SN);
        float h = fmaxf(acc * nd, 0.f);
        *(_Float16*)(U + (size_t)d * 64 + Li * 16 + 2 * t) = (_Float16)h;
        if (Li == 1 && t == 1)
            *(float*)(U + (size_t)d * 64 + 52) = SN;   // exact SN for layers 2/3
    } else if (t == 0) {
        float z0 = b2[0], z1 = b2[1];
#pragma unroll
        for (int c = 0; c < 8; c++) {
            float acc = fmaf(wv[c], T[c], bv[c] * SN);
            float h = fmaxf(acc * nd, 0.f);
            z0 = fmaf(h, W2[c * 2 + 0], z0);
            z1 = fmaf(h, W2[c * 2 + 1], z1);
        }
        float m2 = fmaxf(z0, z1);
        float lse = m2 + logf(__expf(z0 - m2) + __expf(z1 - m2));
        ((float2*)out)[d] = make_float2(z0 - lse, z1 - lse);
    }
}

extern "C" void kernel_launch(void* const* d_in, const int* in_sizes, int n_in,
                              void* d_out, int out_size, void* d_ws, size_t ws_size,
                              hipStream_t stream) {
    const float* x    = (const float*)d_in[0];
    const int*   nidx = (const int*)d_in[1];
    const int*   eidx = (const int*)d_in[3];
    const float* emb  = (const float*)d_in[5];
    const float* W1   = (const float*)d_in[6];
    const float* b1   = (const float*)d_in[7];
    const float* Wq   = (const float*)d_in[8];
    const float* bq   = (const float*)d_in[9];
    const float* Wk   = (const float*)d_in[10];
    const float* bk   = (const float*)d_in[11];
    const float* Wv   = (const float*)d_in[12];
    const float* bv   = (const float*)d_in[13];
    const float* W2   = (const float*)d_in[14];
    const float* b2   = (const float*)d_in[15];
    float* out = (float*)d_out;

    const int n = in_sizes[0] / 16;            // 100000
    const int E = in_sizes[3] / 2;             // 3200000
    const int NS = (n + SBN - 1) / SBN;        // 391
    const int NBLK = (E + CH - 1) / CH;        // 782
    const int GN = (n + 255) / 256;            // 391

    char* wsp = (char*)d_ws;
    char*  A     = wsp;                      wsp += (size_t)n * 32;
    char*  U     = wsp;                      wsp += (size_t)n * 64;
    int*   ebuf  = (int*)wsp;                wsp += (size_t)NS * CAP * 4;
    unsigned int* off = (unsigned int*)wsp;  wsp += (size_t)n * 4;
    int*   gcnt  = (int*)wsp;                wsp += (size_t)NS * 4;

    dim3 blk(256);
    dim3 ga(((size_t)n * 8 + 255) / 256);

    hipMemsetAsync(gcnt, 0, (size_t)NS * 4, stream);
    build_init<<<NBLK + GN, blk, 0, stream>>>(eidx, gcnt, ebuf, E, NS, NBLK,
        x, nidx, emb, W1, b1, A, U, n);
    super_csr<<<NS, blk, 0, stream>>>(ebuf, gcnt, off, A, U, NS, n);

    agg_layer<1, false><<<ga, blk, 0, stream>>>(ebuf, off, A, U,
        Wq, bq, Wk, bk, Wv, bv, W2, b2, out, n);
    agg_layer<2, false><<<ga, blk, 0, stream>>>(ebuf, off, A, U,
        Wq + 8, bq + 8, Wk + 8, bk + 8, Wv + 8, bv + 8, W2, b2, out, n);
    agg_layer<3, true><<<ga, blk, 0, stream>>>(ebuf, off, A, U,
        Wq + 16, bq + 16, Wk + 16, bk + 16, Wv + 16, bv + 16, W2, b2, out, n);
}